// Round 11
// baseline (68.070 us; speedup 1.0000x reference)
//
#include <hip/hip_runtime.h>
#include <math.h>

// Problem constants
#define NSLOT 64
#define ADIM  256
#define NE    16
#define NCLS  100
#define BATCH 256

// ws layout (float offsets)
#define OFF_QK 0u           // [16][256][4]  qk[e][a][l], pre-scaled by 1/16
#define OFF_CP 16384u       // [16]          log1p(count+1)
#define OFF_U  32768u       // [16 e][256 b][256 a]   EXPERT-MAJOR (R10 win)
#define OFF_Z  1081344u     // [256 b][16 e][256 d]

__device__ __forceinline__ float wmax(float v) {
#pragma unroll
  for (int m = 32; m >= 1; m >>= 1) v = fmaxf(v, __shfl_xor(v, m, 64));
  return v;
}
__device__ __forceinline__ float wsum(float v) {
#pragma unroll
  for (int m = 32; m >= 1; m >>= 1) v += __shfl_xor(v, m, 64);
  return v;
}

// ---------------- K1: qk[e][a][l] = (1/16) * sum_d q[e,l,d]*Wk[e,d,a]
__global__ __launch_bounds__(256) void prep_kernel(
    const float* __restrict__ queries, const float* __restrict__ Wk,
    const int* __restrict__ counts, float* __restrict__ qk, float* __restrict__ cp)
{
  __shared__ float smf[1024];       // [dg16][a16][l4]
  const int e  = blockIdx.x;
  const int as = blockIdx.y;
  const int tid = threadIdx.x;
  const int a_loc = tid & 15, dg = tid >> 4;
  const float* __restrict__ qp  = queries + e * 1024 + dg * 16;
  const float* __restrict__ wkp = Wk + (size_t)e * 65536 + (size_t)(dg * 16) * 256 + as * 16 + a_loc;
  float a0 = 0.f, a1 = 0.f, a2 = 0.f, a3 = 0.f;
#pragma unroll
  for (int dd = 0; dd < 16; ++dd) {
    float w = wkp[(size_t)dd * 256];
    a0 += qp[0 * 256 + dd] * w;
    a1 += qp[1 * 256 + dd] * w;
    a2 += qp[2 * 256 + dd] * w;
    a3 += qp[3 * 256 + dd] * w;
  }
  float4 acc; acc.x = a0; acc.y = a1; acc.z = a2; acc.w = a3;
  *(float4*)&smf[tid * 4] = acc;
  __syncthreads();
  if (tid < 64) {
    float s = 0.f;
#pragma unroll
    for (int g = 0; g < 16; ++g) s += smf[g * 64 + tid];
    qk[e * 1024 + as * 64 + tid] = s * 0.0625f;
  }
  if (e == 0 && as == 0 && tid < 16) cp[tid] = log1pf((float)counts[tid] + 1.0f);
}

// ---------------- K2: one block per b, all 16 experts; wave w -> experts (w, w+8).
// Halves LDS score reads (h shared across 2 experts) and staging HBM (x read once).
// grid 256 x 512 thr, ~70KB LDS -> 1 block/CU, 2 waves/SIMD, 8 indep FMA chains/wave.
__global__ __launch_bounds__(512, 2) void attn_kernel(
    const float* __restrict__ x, const float* __restrict__ qk,
    float* __restrict__ U)
{
  __shared__ float Hs[64][256];   // chunk-swizzled: chunk c of row s at (c ^ (s&7))
  __shared__ float pt[64][17];    // p[s][e], stride 17 = conflict-free writes
  const int tid  = threadIdx.x;
  const int lane = tid & 63;
  const int w    = tid >> 6;                 // 0..7
  const int b    = blockIdx.x;

  const float4* __restrict__ x4 = (const float4*)(x + (size_t)b * 16384);
#pragma unroll
  for (int it = 0; it < 8; ++it) {
    int fidx = tid + it * 512;               // 0..4095 float4s
    int s = fidx >> 6, c = fidx & 63;
    *(float4*)&Hs[s][(c ^ (s & 7)) << 2] = x4[fidx];
  }
  __syncthreads();

  // score phase: lane = slot s; experts eA = w, eB = w+8; q via wave-uniform loads
  {
    const int eA = __builtin_amdgcn_readfirstlane(w);
    const int eB = __builtin_amdgcn_readfirstlane(w + 8);
    const float* __restrict__ qA = qk + (size_t)eA * 1024;
    const float* __restrict__ qB = qk + (size_t)eB * 1024;
    float aA0=0,aA1=0,aA2=0,aA3=0,aB0=0,aB1=0,aB2=0,aB3=0;
#pragma unroll 4
    for (int a0 = 0; a0 < 64; ++a0) {
      float4 h = *(const float4*)&Hs[lane][(a0 ^ (lane & 7)) << 2];
      const float4* pa = (const float4*)(qA + a0 * 16);
      const float4* pb = (const float4*)(qB + a0 * 16);
      float4 qa0 = pa[0], qa1 = pa[1], qa2 = pa[2], qa3 = pa[3];
      float4 qb0 = pb[0], qb1 = pb[1], qb2 = pb[2], qb3 = pb[3];
      aA0 += h.x*qa0.x + h.y*qa1.x + h.z*qa2.x + h.w*qa3.x;
      aA1 += h.x*qa0.y + h.y*qa1.y + h.z*qa2.y + h.w*qa3.y;
      aA2 += h.x*qa0.z + h.y*qa1.z + h.z*qa2.z + h.w*qa3.z;
      aA3 += h.x*qa0.w + h.y*qa1.w + h.z*qa2.w + h.w*qa3.w;
      aB0 += h.x*qb0.x + h.y*qb1.x + h.z*qb2.x + h.w*qb3.x;
      aB1 += h.x*qb0.y + h.y*qb1.y + h.z*qb2.y + h.w*qb3.y;
      aB2 += h.x*qb0.z + h.y*qb1.z + h.z*qb2.z + h.w*qb3.z;
      aB3 += h.x*qb0.w + h.y*qb1.w + h.z*qb2.w + h.w*qb3.w;
    }
    float pA = 0.f, pB = 0.f, m, ev;
    m = wmax(aA0); ev = __expf(aA0 - m); pA += ev / wsum(ev);
    m = wmax(aA1); ev = __expf(aA1 - m); pA += ev / wsum(ev);
    m = wmax(aA2); ev = __expf(aA2 - m); pA += ev / wsum(ev);
    m = wmax(aA3); ev = __expf(aA3 - m); pA += ev / wsum(ev);
    m = wmax(aB0); ev = __expf(aB0 - m); pB += ev / wsum(ev);
    m = wmax(aB1); ev = __expf(aB1 - m); pB += ev / wsum(ev);
    m = wmax(aB2); ev = __expf(aB2 - m); pB += ev / wsum(ev);
    m = wmax(aB3); ev = __expf(aB3 - m); pB += ev / wsum(ev);
    pt[lane][w]     = pA * 0.25f;
    pt[lane][w + 8] = pB * 0.25f;
  }
  __syncthreads();

  // u phase: lane = a-quad; wave w accumulates u for its 2 experts via b128 reads.
  // pt[s][w] / pt[s][w+8] are wave-uniform addresses -> LDS broadcast (cheap).
  {
    float4 u0 = {0.f,0.f,0.f,0.f}, u1 = {0.f,0.f,0.f,0.f};
#pragma unroll 8
    for (int s = 0; s < 64; ++s) {
      float4 h = *(const float4*)&Hs[s][(lane ^ (s & 7)) << 2];
      float p0 = pt[s][w], p1 = pt[s][w + 8];
      u0.x += h.x * p0; u0.y += h.y * p0; u0.z += h.z * p0; u0.w += h.w * p0;
      u1.x += h.x * p1; u1.y += h.y * p1; u1.z += h.z * p1; u1.w += h.w * p1;
    }
    // expert-major stores, coalesced b128 per wave
    *(float4*)&U[(size_t)w * 65536 + (size_t)b * 256 + 4 * lane]       = u0;
    *(float4*)&U[(size_t)(w + 8) * 65536 + (size_t)b * 256 + 4 * lane] = u1;
  }
}

// ---------------- K3: per-expert GEMM  Z[b][e][d] = U[e][b][:] . Wv[e][d][:]
// Dense per-expert U (R10). Tile 64(b) x 32(d), K=256 in 4 chunks, reg-prefetch
// of chunk ck+1 over compute of ck. grid 512: bt=i&3, dt=(i>>2)&7, e=i>>5.
__global__ __launch_bounds__(256, 2) void zgemm_kernel(
    const float* __restrict__ U, const float* __restrict__ Wv,
    float* __restrict__ Z)
{
  __shared__ float Us[64][64];   // chunk c of row r at (c ^ ((r>>2)&7))
  __shared__ float Ws[32][64];
  const int tid = threadIdx.x;
  const int i  = blockIdx.x;
  const int bt = i & 3, dt = (i >> 2) & 7, e = i >> 5;
  const int tx = tid & 15, ty = tid >> 4;
  float acc[4][2] = {};

  const float* __restrict__ Ua = U + (size_t)e * 65536 + (size_t)(bt * 64) * 256;
  const float* __restrict__ Wa = Wv + (size_t)e * 65536 + (size_t)(dt * 32) * 256;

  float4 ra[4], rb[2];
#define LOADC(ck) do { \
  _Pragma("unroll") for (int it = 0; it < 4; ++it) { \
    int t2 = tid + it * 256; int row = t2 >> 4, c = t2 & 15; \
    ra[it] = *(const float4*)&Ua[(size_t)row * 256 + (ck) * 64 + c * 4]; } \
  _Pragma("unroll") for (int it = 0; it < 2; ++it) { \
    int t2 = tid + it * 256; int row = t2 >> 4, c = t2 & 15; \
    rb[it] = *(const float4*)&Wa[(size_t)row * 256 + (ck) * 64 + c * 4]; } } while (0)

  LOADC(0);
  for (int ck = 0; ck < 4; ++ck) {
#pragma unroll
    for (int it = 0; it < 4; ++it) {
      int t2 = tid + it * 256; int row = t2 >> 4, c = t2 & 15;
      *(float4*)&Us[row][(c ^ ((row >> 2) & 7)) << 2] = ra[it];
    }
#pragma unroll
    for (int it = 0; it < 2; ++it) {
      int t2 = tid + it * 256; int row = t2 >> 4, c = t2 & 15;
      *(float4*)&Ws[row][(c ^ ((row >> 2) & 7)) << 2] = rb[it];
    }
    __syncthreads();
    if (ck < 3) LOADC(ck + 1);          // in flight across compute
#pragma unroll
    for (int cc = 0; cc < 16; ++cc) {
      float4 A[4], B[2];
#pragma unroll
      for (int ii = 0; ii < 4; ++ii) A[ii] = *(const float4*)&Us[ty * 4 + ii][(cc ^ (ty & 7)) << 2];
#pragma unroll
      for (int j = 0; j < 2; ++j) B[j] = *(const float4*)&Ws[tx * 2 + j][(cc ^ ((tx >> 1) & 7)) << 2];
#pragma unroll
      for (int ii = 0; ii < 4; ++ii)
#pragma unroll
        for (int j = 0; j < 2; ++j)
          acc[ii][j] += A[ii].x*B[j].x + A[ii].y*B[j].y + A[ii].z*B[j].z + A[ii].w*B[j].w;
    }
    __syncthreads();
  }
#undef LOADC

#pragma unroll
  for (int ii = 0; ii < 4; ++ii) {
    float2 r; r.x = acc[ii][0]; r.y = acc[ii][1];
    *(float2*)&Z[(((size_t)(bt * 64 + ty * 4 + ii)) * 16 + e) * 256 + dt * 32 + tx * 2] = r;
  }
}

// ---------------- K4: norms -> top3 -> gate -> final -> logits (single Z)
__global__ __launch_bounds__(512) void final_kernel(
    const float* __restrict__ Z, const float* __restrict__ cp,
    const float* __restrict__ CQ, float* __restrict__ out)
{
  __shared__ float zs[16][260];
  __shared__ float nrm[16];
  __shared__ float fin[256];
  const int tid = threadIdx.x, lane = tid & 63, w = tid >> 6;  // 8 waves
  const int b = blockIdx.x;
  const size_t zb = (size_t)b * 16 * 256;

#pragma unroll
  for (int it = 0; it < 2; ++it) {
    int idx = tid + it * 512;
    int e = idx >> 6, c = idx & 63;
    *(float4*)&zs[e][c * 4] = *(const float4*)&Z[zb + e * 256 + c * 4];
  }
  __syncthreads();

  for (int e = w; e < 16; e += 8) {
    float4 zv = *(const float4*)&zs[e][lane * 4];
    float ss = zv.x*zv.x + zv.y*zv.y + zv.z*zv.z + zv.w*zv.w;
    ss = wsum(ss);
    if (lane == 0) nrm[e] = sqrtf(ss);
  }
  __syncthreads();

  float sc[16];
#pragma unroll
  for (int e = 0; e < 16; ++e) sc[e] = nrm[e] * cp[e];
  int i0 = 0; float v0 = sc[0];
#pragma unroll
  for (int e = 1; e < 16; ++e) if (sc[e] > v0) { v0 = sc[e]; i0 = e; }
  int i1 = -1; float v1 = -3.4e38f;
#pragma unroll
  for (int e = 0; e < 16; ++e) if (e != i0 && sc[e] > v1) { v1 = sc[e]; i1 = e; }
  int i2 = -1; float v2 = -3.4e38f;
#pragma unroll
  for (int e = 0; e < 16; ++e) if (e != i0 && e != i1 && sc[e] > v2) { v2 = sc[e]; i2 = e; }
  float g1 = __expf(v1 - v0), g2 = __expf(v2 - v0);
  float inv = 1.0f / (1.0f + g1 + g2);
  float g0 = inv; g1 *= inv; g2 *= inv;

  if (tid < 256)
    fin[tid] = g0 * zs[i0][tid] + g1 * zs[i1][tid] + g2 * zs[i2][tid];
  __syncthreads();

  float4 f = *(const float4*)&fin[lane * 4];
  for (int c = w; c < NCLS; c += 8) {
    float4 cq = *(const float4*)&CQ[(size_t)c * 256 + lane * 4];
    float part = f.x*cq.x + f.y*cq.y + f.z*cq.z + f.w*cq.w;
    part = wsum(part);
    if (lane == 0) out[(size_t)b * NCLS + c] = part;
  }
}

extern "C" void kernel_launch(void* const* d_in, const int* in_sizes, int n_in,
                              void* d_out, int out_size, void* d_ws, size_t ws_size,
                              hipStream_t stream) {
  const float* x       = (const float*)d_in[0];
  const float* queries = (const float*)d_in[1];
  const float* Wk      = (const float*)d_in[2];
  const float* Wv      = (const float*)d_in[3];
  const float* CQ      = (const float*)d_in[4];
  const int*   counts  = (const int*)d_in[5];
  float* out = (float*)d_out;
  float* ws  = (float*)d_ws;
  float* qk = ws + OFF_QK;
  float* cp = ws + OFF_CP;
  float* U  = ws + OFF_U;
  float* Z  = ws + OFF_Z;

  prep_kernel<<<dim3(16, 16), 256, 0, stream>>>(queries, Wk, counts, qk, cp);
  attn_kernel<<<256, 512, 0, stream>>>(x, qk, U);
  zgemm_kernel<<<512, 256, 0, stream>>>(U, Wv, Z);
  final_kernel<<<256, 512, 0, stream>>>(Z, cp, CQ, out);
}